// Round 9
// baseline (231.451 us; speedup 1.0000x reference)
//
#include <hip/hip_runtime.h>
#include <hip/hip_bf16.h>

#define B_ 2
#define C_ 256
#define NH_ 8
#define D_ 32
#define N_ 4096
#define SCALE_ 0.17677669529663689f
// SCALE * log2(e): folded into Q so softmax is a bare v_exp_f32 per score
#define QSC_ 0.25505277f

typedef __hip_bfloat16 bf16;
typedef __attribute__((ext_vector_type(8))) short sx8;   // 8 bf16 = one MFMA A/B frag
typedef __attribute__((ext_vector_type(4))) short sx4;
typedef __attribute__((ext_vector_type(4))) float fx4;   // MFMA C/D frag

__device__ __forceinline__ float b2f(bf16 x) { return __bfloat162float(x); }
__device__ __forceinline__ bf16 f2b(float x) { return __float2bfloat16(x); }
__device__ __forceinline__ short fbs(float x) { bf16 h = __float2bfloat16(x); return *(short*)&h; }
__device__ __forceinline__ float sbf(short s) { bf16 h = *(bf16*)&s; return __bfloat162float(h); }
// compiler-only ordering barrier; HW DS pipe is in-order per wave (validated
// R7/R8: RAW and WAR through LDS with no lgkmcnt(0) passed bit-exact).
__device__ __forceinline__ void sched_mem_fence() { asm volatile("" ::: "memory"); }

#if __has_builtin(__builtin_amdgcn_exp2f)
__device__ __forceinline__ float fexp2(float x) { return __builtin_amdgcn_exp2f(x); }
#else
__device__ __forceinline__ float fexp2(float x) { return exp2f(x); }
#endif

// ---------------------------------------------------------------------------
// Prep 1: x (fp32, c-major) -> xb[z][p][c] bf16 pos-major (transpose+convert)
// ---------------------------------------------------------------------------
__global__ __launch_bounds__(256)
void convert_x_kernel(const float* __restrict__ spatial,
                      const float* __restrict__ freq,
                      bf16* __restrict__ xb) {
  const int tid = threadIdx.x;
  const int p0 = blockIdx.x * 64;
  const int c0 = blockIdx.y * 64;
  const int z  = blockIdx.z;            // s*B_ + b
  const int s = z >> 1, b = z & 1;
  const float* x = (s == 0) ? spatial : freq;

  __shared__ float ls[64][65];

  const int pp = tid & 63, cb = tid >> 6;
  #pragma unroll
  for (int i = 0; i < 16; ++i) {
    int c = cb + 4 * i;
    ls[c][pp] = x[(size_t)(b * C_ + c0 + c) * N_ + p0 + pp];
  }
  __syncthreads();

  #pragma unroll
  for (int i = 0; i < 2; ++i) {
    int j = tid + 256 * i;              // 0..511
    int p = j >> 3, ck = (j & 7) * 8;
    short tmp[8];
    #pragma unroll
    for (int u = 0; u < 8; ++u) tmp[u] = fbs(ls[ck + u][p]);
    *(sx8*)(xb + ((size_t)z * N_ + p0 + p) * C_ + c0 + ck) = *(sx8*)tmp;
  }
}

// ---------------------------------------------------------------------------
// Prep 2: weights -> bf16. wb = stacked [wq;wk;wv] (768x256), wob = wo.
// ---------------------------------------------------------------------------
__global__ __launch_bounds__(256)
void convert_w_kernel(const float* __restrict__ wq, const float* __restrict__ wk,
                      const float* __restrict__ wv, const float* __restrict__ wo,
                      bf16* __restrict__ wb, bf16* __restrict__ wob) {
  int idx = blockIdx.x * 256 + threadIdx.x;     // 0..262143
  if (idx < 196608) {
    const float* src = (idx < 65536) ? wq : (idx < 131072) ? wk : wv;
    wb[idx] = f2b(src[idx & 65535]);
  } else {
    int off = idx - 196608;
    wob[off] = f2b(wo[off]);
  }
}

// ---------------------------------------------------------------------------
// Kernel 1: QKV projection as MFMA GEMM. D = W (768x256) * x (256x4096) per z.
//   qhf/khf: per-head pos-major [z][h][n][d32]   (Q pre-scaled by QSC_)
//   vhf:     frag-blocked [z][h][n>>5][d>>4][d&15][n&31]
// grid (N_/128, 768/128, 2*B_), block 256 (4 waves, each 64x64)
// ---------------------------------------------------------------------------
__global__ __launch_bounds__(256)
void qkv_gemm_kernel(const bf16* __restrict__ wb, const bf16* __restrict__ xb,
                     const float* __restrict__ bq, const float* __restrict__ bk,
                     const float* __restrict__ bv,
                     bf16* __restrict__ qhf, bf16* __restrict__ khf,
                     bf16* __restrict__ vhf) {
  const int tid = threadIdx.x;
  const int p0 = blockIdx.x * 128;
  const int o0 = blockIdx.y * 128;
  const int z  = blockIdx.z;

  const int lane = tid & 63, w = tid >> 6;
  const int ml = lane & 15, Q4 = (lane >> 4) * 4, Q8 = (lane >> 4) * 8;
  const int ow = (w >> 1) * 64, pw = (w & 1) * 64;

  __shared__ __align__(16) short asb[128 * 72];
  __shared__ __align__(16) short bsb[128 * 72];
  __shared__ float bias_s[128];

  if (tid < 128) {
    int o = o0 + tid;
    bias_s[tid] = (o < 256) ? bq[o] : (o < 512) ? bk[o - 256] : bv[o - 512];
  }

  const fx4 z4 = {0.f, 0.f, 0.f, 0.f};
  fx4 acc[4][4];
  #pragma unroll
  for (int ot = 0; ot < 4; ++ot)
    #pragma unroll
    for (int pt = 0; pt < 4; ++pt) acc[ot][pt] = z4;

  const int sr = tid >> 1, scu = (tid & 1) * 32;
  for (int k0 = 0; k0 < 256; k0 += 64) {
    __syncthreads();
    #pragma unroll
    for (int u = 0; u < 4; ++u) {
      *(sx8*)&asb[sr * 72 + scu + u * 8] =
          *(const sx8*)&wb[(o0 + sr) * 256 + k0 + scu + u * 8];
      *(sx8*)&bsb[sr * 72 + scu + u * 8] =
          *(const sx8*)(xb + ((size_t)z * N_ + p0 + sr) * C_ + k0 + scu + u * 8);
    }
    __syncthreads();
    #pragma unroll
    for (int kk = 0; kk < 2; ++kk) {
      sx8 af[4], bfr[4];
      #pragma unroll
      for (int t = 0; t < 4; ++t)
        af[t] = *(sx8*)&asb[(ow + t * 16 + ml) * 72 + kk * 32 + Q8];
      #pragma unroll
      for (int t = 0; t < 4; ++t)
        bfr[t] = *(sx8*)&bsb[(pw + t * 16 + ml) * 72 + kk * 32 + Q8];
      #pragma unroll
      for (int ot = 0; ot < 4; ++ot)
        #pragma unroll
        for (int pt = 0; pt < 4; ++pt)
          acc[ot][pt] = __builtin_amdgcn_mfma_f32_16x16x32_bf16(
              af[ot], bfr[pt], acc[ot][pt], 0, 0, 0);
    }
  }

  if (o0 < 512) {
    bf16* dst = (o0 < 256) ? qhf : khf;
    const int ob = (o0 < 256) ? o0 : o0 - 256;
    const float scl = (o0 < 256) ? QSC_ : 1.f;
    #pragma unroll
    for (int ot = 0; ot < 4; ++ot) {
      const int og = ob + ow + ot * 16 + Q4;    // global o, head = og>>5
      #pragma unroll
      for (int pt = 0; pt < 4; ++pt) {
        int p = p0 + pw + pt * 16 + ml;
        short tmp[4];
        #pragma unroll
        for (int r = 0; r < 4; ++r)
          tmp[r] = fbs((acc[ot][pt][r] + bias_s[ow + ot * 16 + Q4 + r]) * scl);
        *(sx4*)(dst + (((size_t)z * NH_ + (og >> 5)) * N_ + p) * D_ + (og & 31)) =
            *(sx4*)tmp;
      }
    }
  } else {
    #pragma unroll
    for (int ot = 0; ot < 4; ++ot)
      #pragma unroll
      for (int pt = 0; pt < 4; ++pt) {
        int p = p0 + pw + pt * 16 + ml;
        #pragma unroll
        for (int r = 0; r < 4; ++r) {
          int lo = ow + ot * 16 + Q4 + r;       // local o in [0,128)
          int rho = (o0 - 512) + lo;            // 0..255
          int h = rho >> 5, d = rho & 31;
          size_t basev = ((size_t)z * NH_ + h) * D_ * N_;
          vhf[basev + (size_t)(((p >> 5) * 2) + (d >> 4)) * 512 +
              (d & 15) * 32 + (p & 31)] = f2b(acc[ot][pt][r] + bias_s[lo]);
        }
      }
  }
}

// ---------------------------------------------------------------------------
// Kernel 2: MFMA flash attention, KV-split. Each block handles N_/NSPLIT keys.
// Max-free softmax => partials are pure sums: O=(O1+O2)/(l1+l2).
// Conflict-free XOR-swizzled LDS: kts stride 32 (d-granule ^= n&3),
// pst stride 64 (n-granule ^= ml&7). Shared per-wave pst (WAR-safe, R8).
// NSPLIT==1: writes normalized attoT directly (no partials).
// grid (N_/256, NH_, 4*NSPLIT), block 256 (4 waves, 64 q each)
// ---------------------------------------------------------------------------
template<int NSPLIT>
__global__ __launch_bounds__(256, 4)
void attn_kernel_t(const bf16* __restrict__ qhf, const bf16* __restrict__ khf,
                   const bf16* __restrict__ vhf, bf16* __restrict__ outp,
                   float* __restrict__ lpart) {
  const int tid  = threadIdx.x;
  const int m0   = blockIdx.x * 256;
  const int h    = blockIdx.y;
  const int bz   = blockIdx.z;
  const int sp   = (NSPLIT == 1) ? 0 : (bz >> 2);
  const int z    = (NSPLIT == 1) ? bz : (bz & 3);
  const int s = z >> 1, b = z & 1;
  const int zo = ((1 - s) << 1) | b;    // kv source

  const bf16* qz = qhf + ((size_t)z  * NH_ + h) * N_ * D_;
  const bf16* kz = khf + ((size_t)zo * NH_ + h) * N_ * D_;
  const bf16* vz = vhf + ((size_t)zo * NH_ + h) * D_ * N_;

  const int lane = tid & 63;
  const int w    = tid >> 6;
  const int ml   = lane & 15;
  const int q4   = lane >> 4;           // quad 0..3
  const int Q4   = q4 * 4;
  const int Q8   = q4 * 8;

  // XOR-swizzled, conflict-free LDS
  __shared__ __align__(16) short kts[2][64 * 32];       // 8 KB
  __shared__ __align__(16) short vss[2][4][16 * 36];    // 9 KB
  __shared__ __align__(16) short pst[4][16 * 64];       // 8 KB (per wave)

  const int nlo = sp * (N_ / NSPLIT);
  const int nhi = nlo + N_ / NSPLIT;

  // Q fragments (B-operand): strip s4 -> row m0 + w*64 + s4*16 + ml
  sx8 qf[4];
  #pragma unroll
  for (int s4 = 0; s4 < 4; ++s4)
    qf[s4] = *(const sx8*)(qz + (size_t)(m0 + w * 64 + s4 * 16 + ml) * D_ + Q8);

  sx8 onesf;                            // bf16 1.0 row for the l-sum MFMA
  #pragma unroll
  for (int u = 0; u < 8; ++u) onesf[u] = (short)0x3F80;

  const fx4 z4 = {0.f, 0.f, 0.f, 0.f};
  fx4 acc[4][2];
  #pragma unroll
  for (int s4 = 0; s4 < 4; ++s4) { acc[s4][0] = z4; acc[s4][1] = z4; }
  fx4 lacc[4] = {z4, z4, z4, z4};

  // staging coords (lane-constant swizzles)
  const int srow = tid >> 2;                              // K: row n 0..63
  const int ksw  = ((tid & 3) ^ (srow & 3)) * 8;          //    phys d-granule
  const int vblk = tid >> 6, vrow = (tid >> 2) & 15, vg = (tid & 3) * 8;
  // fragment-read swizzles (lane-constant)
  const int kfg  = (q4 ^ (ml & 3)) * 8;                   // kts read granule
  const int psw  = ml & 7;                                // pst granule XOR
  const int pr0  = ml * 64 + ((q4 ^ psw) * 8);            // pf0 read addr
  const int pr1  = ml * 64 + (((4 + q4) ^ psw) * 8);      // pf1 read addr

  sx8 kpre = *(const sx8*)(kz + (size_t)nlo * D_ + (size_t)tid * 8);
  sx8 vpre = *(const sx8*)(vz + (size_t)nlo * D_ + (size_t)tid * 8);
  *(sx8*)&kts[0][srow * 32 + ksw] = kpre;
  *(sx8*)&vss[0][vblk][vrow * 36 + vg] = vpre;
  __syncthreads();

  int cur = 0;
  for (int n0 = nlo; n0 < nhi; n0 += 64) {
    const bool more = (n0 + 64 < nhi);
    if (more) {
      kpre = *(const sx8*)(kz + (size_t)(n0 + 64) * D_ + (size_t)tid * 8);
      vpre = *(const sx8*)(vz + (size_t)(n0 + 64) * D_ + (size_t)tid * 8);
    }

    // fragments from LDS (shared across all 4 strips)
    sx8 kf[4], vf[2][2];
    #pragma unroll
    for (int t = 0; t < 4; ++t)
      kf[t] = *(sx8*)&kts[cur][(t * 16 + ml) * 32 + kfg];
    #pragma unroll
    for (int dt = 0; dt < 2; ++dt)
      #pragma unroll
      for (int c = 0; c < 2; ++c)
        vf[dt][c] = *(sx8*)&vss[cur][c * 2 + dt][ml * 36 + Q8];

    #pragma unroll
    for (int s4 = 0; s4 < 4; ++s4) {
      fx4 st[4];
      #pragma unroll
      for (int t = 0; t < 4; ++t)
        st[t] = __builtin_amdgcn_mfma_f32_16x16x32_bf16(kf[t], qf[s4], z4, 0, 0, 0);
      #pragma unroll
      for (int t = 0; t < 4; ++t) {
        #pragma unroll
        for (int r = 0; r < 4; ++r) st[t][r] = fexp2(st[t][r]);
        sx4 pk = {fbs(st[t][0]), fbs(st[t][1]), fbs(st[t][2]), fbs(st[t][3])};
        // write granule gidx = 2t + (q4>>1), swizzled by ml&7; offset 4*(q4&1)
        *(sx4*)&pst[w][ml * 64 + (((2 * t + (q4 >> 1)) ^ psw) * 8) +
                       4 * (q4 & 1)] = pk;
      }
      sched_mem_fence();   // order write -> read (HW DS in-order per wave)
      sx8 pf0 = *(sx8*)&pst[w][pr0];
      sx8 pf1 = *(sx8*)&pst[w][pr1];
      sched_mem_fence();   // order read -> next strip's write
      lacc[s4] = __builtin_amdgcn_mfma_f32_16x16x32_bf16(onesf, pf0, lacc[s4], 0, 0, 0);
      lacc[s4] = __builtin_amdgcn_mfma_f32_16x16x32_bf16(onesf, pf1, lacc[s4], 0, 0, 0);
      #pragma unroll
      for (int dt = 0; dt < 2; ++dt) {
        fx4 a = acc[s4][dt];
        a = __builtin_amdgcn_mfma_f32_16x16x32_bf16(vf[dt][0], pf0, a, 0, 0, 0);
        a = __builtin_amdgcn_mfma_f32_16x16x32_bf16(vf[dt][1], pf1, a, 0, 0, 0);
        acc[s4][dt] = a;
      }
    }

    if (more) {
      *(sx8*)&kts[cur ^ 1][srow * 32 + ksw] = kpre;
      *(sx8*)&vss[cur ^ 1][vblk][vrow * 36 + vg] = vpre;
    }
    __syncthreads();
    cur ^= 1;
  }

  // epilogue
  #pragma unroll
  for (int s4 = 0; s4 < 4; ++s4) {
    int col = m0 + w * 64 + s4 * 16 + ml;
    if (NSPLIT == 1) {
      float inv = 1.f / lacc[s4][0];
      #pragma unroll
      for (int dt = 0; dt < 2; ++dt) {
        short tmp[4];
        #pragma unroll
        for (int r = 0; r < 4; ++r) tmp[r] = fbs(acc[s4][dt][r] * inv);
        *(sx4*)(outp + ((size_t)z * N_ + col) * C_ + h * D_ + dt * 16 + Q4) =
            *(sx4*)tmp;
      }
    } else {
      // unnormalized partials: opart[sp][z][h][n][d] bf16, lpart fp32
      size_t ob = (((size_t)(sp * 4 + z) * NH_ + h) * N_ + col) * D_;
      #pragma unroll
      for (int dt = 0; dt < 2; ++dt) {
        short tmp[4];
        #pragma unroll
        for (int r = 0; r < 4; ++r) tmp[r] = fbs(acc[s4][dt][r]);
        *(sx4*)(outp + ob + dt * 16 + Q4) = *(sx4*)tmp;
      }
      if (q4 == 0)
        lpart[((size_t)(sp * 4 + z) * NH_ + h) * N_ + col] = lacc[s4][0];
    }
  }
}

// ---------------------------------------------------------------------------
// Combine (split=2 only): attoT[z][n][c] = (O1+O2)/(l1+l2). grid 2048 x 256.
// ---------------------------------------------------------------------------
__global__ __launch_bounds__(256)
void combine_kernel(const bf16* __restrict__ opart,
                    const float* __restrict__ lpart,
                    bf16* __restrict__ attoT) {
  int flat = blockIdx.x * 256 + threadIdx.x;    // 0 .. 4*4096*32-1
  int g = flat & 31;                            // c-granule (8 channels)
  int n = (flat >> 5) & (N_ - 1);
  int z = flat >> 17;
  int h = g >> 2, d0 = (g & 3) * 8;

  size_t i0 = (((size_t)(0 + z) * NH_ + h) * N_ + n) * D_ + d0;
  size_t i1 = (((size_t)(4 + z) * NH_ + h) * N_ + n) * D_ + d0;
  sx8 a = *(const sx8*)(opart + i0);
  sx8 c = *(const sx8*)(opart + i1);
  float l = lpart[((size_t)(0 + z) * NH_ + h) * N_ + n] +
            lpart[((size_t)(4 + z) * NH_ + h) * N_ + n];
  float inv = 1.f / l;
  short tmp[8];
  #pragma unroll
  for (int u = 0; u < 8; ++u) tmp[u] = fbs((sbf(a[u]) + sbf(c[u])) * inv);
  *(sx8*)(attoT + ((size_t)z * N_ + n) * C_ + g * 8) = *(sx8*)tmp;
}

// ---------------------------------------------------------------------------
// Kernel 3: out_proj as MFMA GEMM. D = Wo * (attS + attF), residuals fused.
// ---------------------------------------------------------------------------
__global__ __launch_bounds__(256)
void out_proj_kernel(const bf16* __restrict__ wob, const bf16* __restrict__ attoT,
                     const float* __restrict__ spatial,
                     const float* __restrict__ freq,
                     const float* __restrict__ bo, float* __restrict__ out) {
  const int tid = threadIdx.x;
  const int p0 = blockIdx.x * 128;
  const int o0 = blockIdx.y * 64;
  const int b  = blockIdx.z;

  const int lane = tid & 63, w = tid >> 6;
  const int ml = lane & 15, Q4 = (lane >> 4) * 4, Q8 = (lane >> 4) * 8;
  const int ow = (w >> 1) * 32, pw = (w & 1) * 64;

  __shared__ __align__(16) short asb[64 * 72];
  __shared__ __align__(16) short bsb[128 * 72];
  __shared__ float bo_s[64];

  if (tid < 64) bo_s[tid] = 2.f * bo[o0 + tid];

  const bf16* at0 = attoT + (size_t)(0 + b) * N_ * C_;   // s=0 slice
  const bf16* at1 = attoT + (size_t)(2 + b) * N_ * C_;   // s=1 slice

  const fx4 z4 = {0.f, 0.f, 0.f, 0.f};
  fx4 acc[2][4];
  #pragma unroll
  for (int ot = 0; ot < 2; ++ot)
    #pragma unroll
    for (int pt = 0; pt < 4; ++pt) acc[ot][pt] = z4;

  for (int k0 = 0; k0 < 256; k0 += 64) {
    __syncthreads();
    #pragma unroll
    for (int i = 0; i < 2; ++i) {
      int j = tid + 256 * i;            // 0..511
      int r = j >> 3, cu = (j & 7) * 8;
      *(sx8*)&asb[r * 72 + cu] = *(const sx8*)&wob[(o0 + r) * 256 + k0 + cu];
    }
    #pragma unroll
    for (int i = 0; i < 4; ++i) {
      int j = tid + 256 * i;            // 0..1023
      int p = j >> 3, cu = (j & 7) * 8;
      sx8 va = *(const sx8*)(at0 + (size_t)(p0 + p) * C_ + k0 + cu);
      sx8 vb2 = *(const sx8*)(at1 + (size_t)(p0 + p) * C_ + k0 + cu);
      short tmp[8];
      #pragma unroll
      for (int u = 0; u < 8; ++u) tmp[u] = fbs(sbf(va[u]) + sbf(vb2[u]));
      *(sx8*)&bsb[p * 72 + cu] = *(sx8*)tmp;
    }
    __syncthreads();
    #pragma unroll
    for (int kk = 0; kk < 2; ++kk) {
      sx8 af[2], bfr[4];
      #pragma unroll
      for (int t = 0; t < 2; ++t)
        af[t] = *(sx8*)&asb[(ow + t * 16 + ml) * 72 + kk * 32 + Q8];
      #pragma unroll
      for (int t = 0; t < 4; ++t)
        bfr[t] = *(sx8*)&bsb[(pw + t * 16 + ml) * 72 + kk * 32 + Q8];
      #pragma unroll
      for (int ot = 0; ot < 2; ++ot)
        #pragma unroll
        for (int pt = 0; pt < 4; ++pt)
          acc[ot][pt] = __builtin_amdgcn_mfma_f32_16x16x32_bf16(
              af[ot], bfr[pt], acc[ot][pt], 0, 0, 0);
    }
  }

  #pragma unroll
  for (int ot = 0; ot < 2; ++ot)
    #pragma unroll
    for (int pt = 0; pt < 4; ++pt) {
      int p = p0 + pw + pt * 16 + ml;
      #pragma unroll
      for (int r = 0; r < 4; ++r) {
        int ol = ow + ot * 16 + Q4 + r;
        size_t off = ((size_t)b * C_ + o0 + ol) * N_ + p;
        out[off] = acc[ot][pt][r] + bo_s[ol] + spatial[off] + freq[off];
      }
    }
}

extern "C" void kernel_launch(void* const* d_in, const int* in_sizes, int n_in,
                              void* d_out, int out_size, void* d_ws, size_t ws_size,
                              hipStream_t stream) {
  const float* spatial = (const float*)d_in[0];
  const float* freq    = (const float*)d_in[1];
  const float* wq = (const float*)d_in[2];
  const float* bq = (const float*)d_in[3];
  const float* wk = (const float*)d_in[4];
  const float* bk = (const float*)d_in[5];
  const float* wv = (const float*)d_in[6];
  const float* bv = (const float*)d_in[7];
  const float* wo = (const float*)d_in[8];
  const float* bo = (const float*)d_in[9];
  float* out = (float*)d_out;

  // workspace layout (bf16 elements unless noted)
  const size_t SZ = (size_t)2 * B_ * N_ * C_;   // 4.19M elems = 8.4 MB
  bf16* xb    = (bf16*)d_ws;                    // [z][p][c]
  bf16* qhf   = xb + SZ;                        // [z][h][n][d]
  bf16* khf   = qhf + SZ;                       // [z][h][n][d]
  bf16* vhf   = khf + SZ;                       // [z][h] frag-blocked
  bf16* attoT = vhf + SZ;                       // [z][p][c]
  bf16* wb    = attoT + SZ;                     // [768][256]
  bf16* wob   = wb + 768 * 256;                 // [256][256]
  bf16* opart = wob + 256 * 256;                // [2][z][h][n][d]
  const size_t OP = (size_t)2 * 4 * NH_ * N_ * D_;      // 8.39M elems
  float* lpart = (float*)(opart + OP);          // [2][z][h][n] fp32
  const size_t LP = (size_t)2 * 4 * NH_ * N_;
  size_t need2 = (size_t)((char*)(lpart + LP) - (char*)d_ws);
  const bool split2 = (ws_size >= need2);

  convert_w_kernel<<<dim3(1024), 256, 0, stream>>>(wq, wk, wv, wo, wb, wob);
  convert_x_kernel<<<dim3(N_ / 64, C_ / 64, 2 * B_), 256, 0, stream>>>(
      spatial, freq, xb);
  qkv_gemm_kernel<<<dim3(N_ / 128, 768 / 128, 2 * B_), 256, 0, stream>>>(
      wb, xb, bq, bk, bv, qhf, khf, vhf);
  if (split2) {
    attn_kernel_t<2><<<dim3(N_ / 256, NH_, 8), 256, 0, stream>>>(
        qhf, khf, vhf, opart, lpart);
    combine_kernel<<<dim3(2048), 256, 0, stream>>>(opart, lpart, attoT);
  } else {
    attn_kernel_t<1><<<dim3(N_ / 256, NH_, 4), 256, 0, stream>>>(
        qhf, khf, vhf, attoT, nullptr);
  }
  out_proj_kernel<<<dim3(N_ / 128, C_ / 64, B_), 256, 0, stream>>>(
      wob, attoT, spatial, freq, bo, out);
}

// Round 10
// 227.432 us; speedup vs baseline: 1.0177x; 1.0177x over previous
//
#include <hip/hip_runtime.h>
#include <hip/hip_bf16.h>

#define B_ 2
#define C_ 256
#define NH_ 8
#define D_ 32
#define N_ 4096
#define SCALE_ 0.17677669529663689f
// SCALE * log2(e): folded into Q so softmax is a bare v_exp_f32 per score
#define QSC_ 0.25505277f

typedef __hip_bfloat16 bf16;
typedef __attribute__((ext_vector_type(8))) short sx8;   // 8 bf16 = one MFMA A/B frag
typedef __attribute__((ext_vector_type(4))) short sx4;
typedef __attribute__((ext_vector_type(4))) float fx4;   // MFMA C/D frag
typedef __attribute__((ext_vector_type(4))) int ix4;

__device__ __forceinline__ float b2f(bf16 x) { return __bfloat162float(x); }
__device__ __forceinline__ bf16 f2b(float x) { return __float2bfloat16(x); }
__device__ __forceinline__ short fbs(float x) { bf16 h = __float2bfloat16(x); return *(short*)&h; }
__device__ __forceinline__ float sbf(short s) { bf16 h = *(bf16*)&s; return __bfloat162float(h); }

#if __has_builtin(__builtin_amdgcn_exp2f)
__device__ __forceinline__ float fexp2(float x) { return __builtin_amdgcn_exp2f(x); }
#else
__device__ __forceinline__ float fexp2(float x) { return exp2f(x); }
#endif

// pack two f32 -> one dword of two bf16 (low = first)
__device__ __forceinline__ unsigned pkbf(float x, float y) {
  unsigned a = (unsigned short)fbs(x);
  unsigned b = (unsigned short)fbs(y);
  return a | (b << 16);
}
// gfx950 MFMA-transpose swaps (VALU cross-lane, not DS pipe):
// permlane32_swap: hi-32 of a <-> lo-32 of b
// permlane16_swap: odd 16-rows of a <-> even 16-rows of b
__device__ __forceinline__ void pl32swap(unsigned &a, unsigned &b) {
  asm volatile("v_permlane32_swap_b32 %0, %1" : "+v"(a), "+v"(b));
}
__device__ __forceinline__ void pl16swap(unsigned &a, unsigned &b) {
  asm volatile("v_permlane16_swap_b32 %0, %1" : "+v"(a), "+v"(b));
}

// ---------------------------------------------------------------------------
// Prep 1: x (fp32, c-major) -> xb[z][p][c] bf16 pos-major (transpose+convert)
// ---------------------------------------------------------------------------
__global__ __launch_bounds__(256)
void convert_x_kernel(const float* __restrict__ spatial,
                      const float* __restrict__ freq,
                      bf16* __restrict__ xb) {
  const int tid = threadIdx.x;
  const int p0 = blockIdx.x * 64;
  const int c0 = blockIdx.y * 64;
  const int z  = blockIdx.z;            // s*B_ + b
  const int s = z >> 1, b = z & 1;
  const float* x = (s == 0) ? spatial : freq;

  __shared__ float ls[64][65];

  const int pp = tid & 63, cb = tid >> 6;
  #pragma unroll
  for (int i = 0; i < 16; ++i) {
    int c = cb + 4 * i;
    ls[c][pp] = x[(size_t)(b * C_ + c0 + c) * N_ + p0 + pp];
  }
  __syncthreads();

  #pragma unroll
  for (int i = 0; i < 2; ++i) {
    int j = tid + 256 * i;              // 0..511
    int p = j >> 3, ck = (j & 7) * 8;
    short tmp[8];
    #pragma unroll
    for (int u = 0; u < 8; ++u) tmp[u] = fbs(ls[ck + u][p]);
    *(sx8*)(xb + ((size_t)z * N_ + p0 + p) * C_ + c0 + ck) = *(sx8*)tmp;
  }
}

// ---------------------------------------------------------------------------
// Prep 2: weights -> bf16. wb = stacked [wq;wk;wv] (768x256), wob = wo.
// ---------------------------------------------------------------------------
__global__ __launch_bounds__(256)
void convert_w_kernel(const float* __restrict__ wq, const float* __restrict__ wk,
                      const float* __restrict__ wv, const float* __restrict__ wo,
                      bf16* __restrict__ wb, bf16* __restrict__ wob) {
  int idx = blockIdx.x * 256 + threadIdx.x;     // 0..262143
  if (idx < 196608) {
    const float* src = (idx < 65536) ? wq : (idx < 131072) ? wk : wv;
    wb[idx] = f2b(src[idx & 65535]);
  } else {
    int off = idx - 196608;
    wob[off] = f2b(wo[off]);
  }
}

// ---------------------------------------------------------------------------
// Kernel 1: QKV projection as MFMA GEMM. D = W (768x256) * x (256x4096) per z.
//   qhf/khf: per-head pos-major [z][h][n][d32]   (Q pre-scaled by QSC_)
//   vhf:     frag-blocked [z][h][n>>5][d>>4][d&15][n&31]
// grid (N_/128, 768/128, 2*B_), block 256 (4 waves, each 64x64)
// ---------------------------------------------------------------------------
__global__ __launch_bounds__(256)
void qkv_gemm_kernel(const bf16* __restrict__ wb, const bf16* __restrict__ xb,
                     const float* __restrict__ bq, const float* __restrict__ bk,
                     const float* __restrict__ bv,
                     bf16* __restrict__ qhf, bf16* __restrict__ khf,
                     bf16* __restrict__ vhf) {
  const int tid = threadIdx.x;
  const int p0 = blockIdx.x * 128;
  const int o0 = blockIdx.y * 128;
  const int z  = blockIdx.z;

  const int lane = tid & 63, w = tid >> 6;
  const int ml = lane & 15, Q4 = (lane >> 4) * 4, Q8 = (lane >> 4) * 8;
  const int ow = (w >> 1) * 64, pw = (w & 1) * 64;

  __shared__ __align__(16) short asb[128 * 72];
  __shared__ __align__(16) short bsb[128 * 72];
  __shared__ float bias_s[128];

  if (tid < 128) {
    int o = o0 + tid;
    bias_s[tid] = (o < 256) ? bq[o] : (o < 512) ? bk[o - 256] : bv[o - 512];
  }

  const fx4 z4 = {0.f, 0.f, 0.f, 0.f};
  fx4 acc[4][4];
  #pragma unroll
  for (int ot = 0; ot < 4; ++ot)
    #pragma unroll
    for (int pt = 0; pt < 4; ++pt) acc[ot][pt] = z4;

  const int sr = tid >> 1, scu = (tid & 1) * 32;
  for (int k0 = 0; k0 < 256; k0 += 64) {
    __syncthreads();
    #pragma unroll
    for (int u = 0; u < 4; ++u) {
      *(sx8*)&asb[sr * 72 + scu + u * 8] =
          *(const sx8*)&wb[(o0 + sr) * 256 + k0 + scu + u * 8];
      *(sx8*)&bsb[sr * 72 + scu + u * 8] =
          *(const sx8*)(xb + ((size_t)z * N_ + p0 + sr) * C_ + k0 + scu + u * 8);
    }
    __syncthreads();
    #pragma unroll
    for (int kk = 0; kk < 2; ++kk) {
      sx8 af[4], bfr[4];
      #pragma unroll
      for (int t = 0; t < 4; ++t)
        af[t] = *(sx8*)&asb[(ow + t * 16 + ml) * 72 + kk * 32 + Q8];
      #pragma unroll
      for (int t = 0; t < 4; ++t)
        bfr[t] = *(sx8*)&bsb[(pw + t * 16 + ml) * 72 + kk * 32 + Q8];
      #pragma unroll
      for (int ot = 0; ot < 4; ++ot)
        #pragma unroll
        for (int pt = 0; pt < 4; ++pt)
          acc[ot][pt] = __builtin_amdgcn_mfma_f32_16x16x32_bf16(
              af[ot], bfr[pt], acc[ot][pt], 0, 0, 0);
    }
  }

  if (o0 < 512) {
    bf16* dst = (o0 < 256) ? qhf : khf;
    const int ob = (o0 < 256) ? o0 : o0 - 256;
    const float scl = (o0 < 256) ? QSC_ : 1.f;
    #pragma unroll
    for (int ot = 0; ot < 4; ++ot) {
      const int og = ob + ow + ot * 16 + Q4;    // global o, head = og>>5
      #pragma unroll
      for (int pt = 0; pt < 4; ++pt) {
        int p = p0 + pw + pt * 16 + ml;
        short tmp[4];
        #pragma unroll
        for (int r = 0; r < 4; ++r)
          tmp[r] = fbs((acc[ot][pt][r] + bias_s[ow + ot * 16 + Q4 + r]) * scl);
        *(sx4*)(dst + (((size_t)z * NH_ + (og >> 5)) * N_ + p) * D_ + (og & 31)) =
            *(sx4*)tmp;
      }
    }
  } else {
    #pragma unroll
    for (int ot = 0; ot < 4; ++ot)
      #pragma unroll
      for (int pt = 0; pt < 4; ++pt) {
        int p = p0 + pw + pt * 16 + ml;
        #pragma unroll
        for (int r = 0; r < 4; ++r) {
          int lo = ow + ot * 16 + Q4 + r;       // local o in [0,128)
          int rho = (o0 - 512) + lo;            // 0..255
          int h = rho >> 5, d = rho & 31;
          size_t basev = ((size_t)z * NH_ + h) * D_ * N_;
          vhf[basev + (size_t)(((p >> 5) * 2) + (d >> 4)) * 512 +
              (d & 15) * 32 + (p & 31)] = f2b(acc[ot][pt][r] + bias_s[lo]);
        }
      }
  }
}

// ---------------------------------------------------------------------------
// Kernel 2: MFMA flash attention. P^T C-layout -> B-operand transform done
// IN REGISTERS via gfx950 v_permlane{32,16}_swap_b32 (VALU, not DS pipe):
//   tiles (t, t+1) packed dwords: pl32swap then pl16swap yields (d0, d2);
//   the other packed pair yields (d1, d3). No P LDS round-trip at all.
// K/V staged in double-buffered LDS; max-free softmax (QSC_ in Q);
// l via ones-row MFMA. grid (N_/256, NH_, 4), block 256 (4 waves, 64 q each)
// ---------------------------------------------------------------------------
__global__ __launch_bounds__(256, 2)
void attn_kernel(const bf16* __restrict__ qhf, const bf16* __restrict__ khf,
                 const bf16* __restrict__ vhf, bf16* __restrict__ attoT) {
  const int tid  = threadIdx.x;
  const int m0   = blockIdx.x * 256;
  const int h    = blockIdx.y;
  const int z    = blockIdx.z;          // s*B_ + b
  const int s = z >> 1, b = z & 1;
  const int zo = ((1 - s) << 1) | b;    // kv source

  const bf16* qz = qhf + ((size_t)z  * NH_ + h) * N_ * D_;
  const bf16* kz = khf + ((size_t)zo * NH_ + h) * N_ * D_;
  const bf16* vz = vhf + ((size_t)zo * NH_ + h) * D_ * N_;

  const int lane = tid & 63;
  const int w    = tid >> 6;
  const int ml   = lane & 15;
  const int q4   = lane >> 4;           // quad 0..3
  const int Q4   = q4 * 4;
  const int Q8   = q4 * 8;

  // double-buffered K/V tiles only (no P buffer any more)
  __shared__ __align__(16) short kts[2][64 * 32];       // 8 KB (XOR-swizzled)
  __shared__ __align__(16) short vss[2][4][16 * 36];    // 9 KB

  // Q fragments (B-operand): strip s4 -> row m0 + w*64 + s4*16 + ml
  sx8 qf[4];
  #pragma unroll
  for (int s4 = 0; s4 < 4; ++s4)
    qf[s4] = *(const sx8*)(qz + (size_t)(m0 + w * 64 + s4 * 16 + ml) * D_ + Q8);

  sx8 onesf;                            // bf16 1.0 row for the l-sum MFMA
  #pragma unroll
  for (int u = 0; u < 8; ++u) onesf[u] = (short)0x3F80;

  const fx4 z4 = {0.f, 0.f, 0.f, 0.f};
  fx4 acc[4][2];
  #pragma unroll
  for (int s4 = 0; s4 < 4; ++s4) { acc[s4][0] = z4; acc[s4][1] = z4; }
  fx4 lacc[4] = {z4, z4, z4, z4};

  // staging coords (lane-constant swizzles)
  const int srow = tid >> 2;                              // K: row n 0..63
  const int ksw  = ((tid & 3) ^ (srow & 3)) * 8;          //    phys d-granule
  const int vblk = tid >> 6, vrow = (tid >> 2) & 15, vg = (tid & 3) * 8;
  const int kfg  = (q4 ^ (ml & 3)) * 8;                   // kts read granule

  sx8 kpre = *(const sx8*)(kz + (size_t)tid * 8);
  sx8 vpre = *(const sx8*)(vz + (size_t)tid * 8);
  *(sx8*)&kts[0][srow * 32 + ksw] = kpre;
  *(sx8*)&vss[0][vblk][vrow * 36 + vg] = vpre;
  __syncthreads();

  int cur = 0;
  for (int n0 = 0; n0 < N_; n0 += 64) {
    const bool more = (n0 + 64 < N_);
    if (more) {
      kpre = *(const sx8*)(kz + (size_t)(n0 + 64) * D_ + (size_t)tid * 8);
      vpre = *(const sx8*)(vz + (size_t)(n0 + 64) * D_ + (size_t)tid * 8);
    }

    // fragments from LDS (shared across all 4 strips)
    sx8 kf[4], vf[2][2];
    #pragma unroll
    for (int t = 0; t < 4; ++t)
      kf[t] = *(sx8*)&kts[cur][(t * 16 + ml) * 32 + kfg];
    #pragma unroll
    for (int dt = 0; dt < 2; ++dt)
      #pragma unroll
      for (int c = 0; c < 2; ++c)
        vf[dt][c] = *(sx8*)&vss[cur][c * 2 + dt][ml * 36 + Q8];

    #pragma unroll
    for (int s4 = 0; s4 < 4; ++s4) {
      fx4 st[4];
      #pragma unroll
      for (int t = 0; t < 4; ++t)
        st[t] = __builtin_amdgcn_mfma_f32_16x16x32_bf16(kf[t], qf[s4], z4, 0, 0, 0);

      // exp + pack each tile's 4 values into 2 dwords (bf16 pairs, n asc.)
      unsigned T[4][2];
      #pragma unroll
      for (int t = 0; t < 4; ++t) {
        float e0 = fexp2(st[t][0]), e1 = fexp2(st[t][1]);
        float e2 = fexp2(st[t][2]), e3 = fexp2(st[t][3]);
        T[t][0] = pkbf(e0, e1);
        T[t][1] = pkbf(e2, e3);
      }
      // in-register C-layout -> B-operand transform (2 swaps per dword pair)
      pl32swap(T[0][0], T[1][0]); pl16swap(T[0][0], T[1][0]);  // -> d0, d2
      pl32swap(T[0][1], T[1][1]); pl16swap(T[0][1], T[1][1]);  // -> d1, d3
      pl32swap(T[2][0], T[3][0]); pl16swap(T[2][0], T[3][0]);
      pl32swap(T[2][1], T[3][1]); pl16swap(T[2][1], T[3][1]);
      ix4 p0 = {(int)T[0][0], (int)T[0][1], (int)T[1][0], (int)T[1][1]};
      ix4 p1 = {(int)T[2][0], (int)T[2][1], (int)T[3][0], (int)T[3][1]};
      sx8 pf0 = *(sx8*)&p0;
      sx8 pf1 = *(sx8*)&p1;

      lacc[s4] = __builtin_amdgcn_mfma_f32_16x16x32_bf16(onesf, pf0, lacc[s4], 0, 0, 0);
      lacc[s4] = __builtin_amdgcn_mfma_f32_16x16x32_bf16(onesf, pf1, lacc[s4], 0, 0, 0);
      #pragma unroll
      for (int dt = 0; dt < 2; ++dt) {
        fx4 a = acc[s4][dt];
        a = __builtin_amdgcn_mfma_f32_16x16x32_bf16(vf[dt][0], pf0, a, 0, 0, 0);
        a = __builtin_amdgcn_mfma_f32_16x16x32_bf16(vf[dt][1], pf1, a, 0, 0, 0);
        acc[s4][dt] = a;
      }
    }

    // write prefetched next tile into the idle buffer, then ONE barrier
    if (more) {
      *(sx8*)&kts[cur ^ 1][srow * 32 + ksw] = kpre;
      *(sx8*)&vss[cur ^ 1][vblk][vrow * 36 + vg] = vpre;
    }
    __syncthreads();
    cur ^= 1;
  }

  // epilogue: l for this lane's query column is lacc[s4][0] (all rows equal)
  #pragma unroll
  for (int s4 = 0; s4 < 4; ++s4) {
    float inv = 1.f / lacc[s4][0];
    int col = m0 + w * 64 + s4 * 16 + ml;
    #pragma unroll
    for (int dt = 0; dt < 2; ++dt) {
      short tmp[4];
      #pragma unroll
      for (int r = 0; r < 4; ++r) tmp[r] = fbs(acc[s4][dt][r] * inv);
      *(sx4*)(attoT + ((size_t)z * N_ + col) * C_ + h * D_ + dt * 16 + Q4) =
          *(sx4*)tmp;
    }
  }
}

// ---------------------------------------------------------------------------
// Kernel 3: out_proj as MFMA GEMM. D = Wo * (attS + attF), residuals fused.
// ---------------------------------------------------------------------------
__global__ __launch_bounds__(256)
void out_proj_kernel(const bf16* __restrict__ wob, const bf16* __restrict__ attoT,
                     const float* __restrict__ spatial,
                     const float* __restrict__ freq,
                     const float* __restrict__ bo, float* __restrict__ out) {
  const int tid = threadIdx.x;
  const int p0 = blockIdx.x * 128;
  const int o0 = blockIdx.y * 64;
  const int b  = blockIdx.z;

  const int lane = tid & 63, w = tid >> 6;
  const int ml = lane & 15, Q4 = (lane >> 4) * 4, Q8 = (lane >> 4) * 8;
  const int ow = (w >> 1) * 32, pw = (w & 1) * 64;

  __shared__ __align__(16) short asb[64 * 72];
  __shared__ __align__(16) short bsb[128 * 72];
  __shared__ float bo_s[64];

  if (tid < 64) bo_s[tid] = 2.f * bo[o0 + tid];

  const bf16* at0 = attoT + (size_t)(0 + b) * N_ * C_;   // s=0 slice
  const bf16* at1 = attoT + (size_t)(2 + b) * N_ * C_;   // s=1 slice

  const fx4 z4 = {0.f, 0.f, 0.f, 0.f};
  fx4 acc[2][4];
  #pragma unroll
  for (int ot = 0; ot < 2; ++ot)
    #pragma unroll
    for (int pt = 0; pt < 4; ++pt) acc[ot][pt] = z4;

  for (int k0 = 0; k0 < 256; k0 += 64) {
    __syncthreads();
    #pragma unroll
    for (int i = 0; i < 2; ++i) {
      int j = tid + 256 * i;            // 0..511
      int r = j >> 3, cu = (j & 7) * 8;
      *(sx8*)&asb[r * 72 + cu] = *(const sx8*)&wob[(o0 + r) * 256 + k0 + cu];
    }
    #pragma unroll
    for (int i = 0; i < 4; ++i) {
      int j = tid + 256 * i;            // 0..1023
      int p = j >> 3, cu = (j & 7) * 8;
      sx8 va = *(const sx8*)(at0 + (size_t)(p0 + p) * C_ + k0 + cu);
      sx8 vb2 = *(const sx8*)(at1 + (size_t)(p0 + p) * C_ + k0 + cu);
      short tmp[8];
      #pragma unroll
      for (int u = 0; u < 8; ++u) tmp[u] = fbs(sbf(va[u]) + sbf(vb2[u]));
      *(sx8*)&bsb[p * 72 + cu] = *(sx8*)tmp;
    }
    __syncthreads();
    #pragma unroll
    for (int kk = 0; kk < 2; ++kk) {
      sx8 af[2], bfr[4];
      #pragma unroll
      for (int t = 0; t < 2; ++t)
        af[t] = *(sx8*)&asb[(ow + t * 16 + ml) * 72 + kk * 32 + Q8];
      #pragma unroll
      for (int t = 0; t < 4; ++t)
        bfr[t] = *(sx8*)&bsb[(pw + t * 16 + ml) * 72 + kk * 32 + Q8];
      #pragma unroll
      for (int ot = 0; ot < 2; ++ot)
        #pragma unroll
        for (int pt = 0; pt < 4; ++pt)
          acc[ot][pt] = __builtin_amdgcn_mfma_f32_16x16x32_bf16(
              af[ot], bfr[pt], acc[ot][pt], 0, 0, 0);
    }
  }

  #pragma unroll
  for (int ot = 0; ot < 2; ++ot)
    #pragma unroll
    for (int pt = 0; pt < 4; ++pt) {
      int p = p0 + pw + pt * 16 + ml;
      #pragma unroll
      for (int r = 0; r < 4; ++r) {
        int ol = ow + ot * 16 + Q4 + r;
        size_t off = ((size_t)b * C_ + o0 + ol) * N_ + p;
        out[off] = acc[ot][pt][r] + bo_s[ol] + spatial[off] + freq[off];
      }
    }
}

extern "C" void kernel_launch(void* const* d_in, const int* in_sizes, int n_in,
                              void* d_out, int out_size, void* d_ws, size_t ws_size,
                              hipStream_t stream) {
  const float* spatial = (const float*)d_in[0];
  const float* freq    = (const float*)d_in[1];
  const float* wq = (const float*)d_in[2];
  const float* bq = (const float*)d_in[3];
  const float* wk = (const float*)d_in[4];
  const float* bk = (const float*)d_in[5];
  const float* wv = (const float*)d_in[6];
  const float* bv = (const float*)d_in[7];
  const float* wo = (const float*)d_in[8];
  const float* bo = (const float*)d_in[9];
  float* out = (float*)d_out;

  // workspace layout (bf16 elements)
  const size_t SZ = (size_t)2 * B_ * N_ * C_;   // 4.19M elems = 8.4 MB
  bf16* xb    = (bf16*)d_ws;                    // [z][p][c]
  bf16* qhf   = xb + SZ;                        // [z][h][n][d]
  bf16* khf   = qhf + SZ;                       // [z][h][n][d]
  bf16* vhf   = khf + SZ;                       // [z][h] frag-blocked
  bf16* attoT = vhf + SZ;                       // [z][p][c]
  bf16* wb    = attoT + SZ;                     // [768][256]
  bf16* wob   = wb + 768 * 256;                 // [256][256]

  convert_w_kernel<<<dim3(1024), 256, 0, stream>>>(wq, wk, wv, wo, wb, wob);
  convert_x_kernel<<<dim3(N_ / 64, C_ / 64, 2 * B_), 256, 0, stream>>>(
      spatial, freq, xb);
  qkv_gemm_kernel<<<dim3(N_ / 128, 768 / 128, 2 * B_), 256, 0, stream>>>(
      wb, xb, bq, bk, bv, qhf, khf, vhf);
  attn_kernel<<<dim3(N_ / 256, NH_, 2 * B_), 256, 0, stream>>>(
      qhf, khf, vhf, attoT);
  out_proj_kernel<<<dim3(N_ / 128, C_ / 64, B_), 256, 0, stream>>>(
      wob, attoT, spatial, freq, bo, out);
}

// Round 11
// 210.610 us; speedup vs baseline: 1.0990x; 1.0799x over previous
//
#include <hip/hip_runtime.h>
#include <hip/hip_bf16.h>

#define B_ 2
#define C_ 256
#define NH_ 8
#define D_ 32
#define N_ 4096
#define SCALE_ 0.17677669529663689f
// SCALE * log2(e): folded into Q so softmax is a bare v_exp_f32 per score
#define QSC_ 0.25505277f

typedef __hip_bfloat16 bf16;
typedef __attribute__((ext_vector_type(8))) short sx8;   // 8 bf16 = one MFMA A/B frag
typedef __attribute__((ext_vector_type(4))) short sx4;
typedef __attribute__((ext_vector_type(4))) float fx4;   // MFMA C/D frag
typedef __attribute__((ext_vector_type(4))) int ix4;

__device__ __forceinline__ float b2f(bf16 x) { return __bfloat162float(x); }
__device__ __forceinline__ bf16 f2b(float x) { return __float2bfloat16(x); }
__device__ __forceinline__ short fbs(float x) { bf16 h = __float2bfloat16(x); return *(short*)&h; }
__device__ __forceinline__ float sbf(short s) { bf16 h = *(bf16*)&s; return __bfloat162float(h); }

#if __has_builtin(__builtin_amdgcn_exp2f)
__device__ __forceinline__ float fexp2(float x) { return __builtin_amdgcn_exp2f(x); }
#else
__device__ __forceinline__ float fexp2(float x) { return exp2f(x); }
#endif

// pack two f32 -> one dword of two bf16 by TRUNCATION (1 VALU op via v_perm).
// P in (0,1]; trunc error <= 2^-8 rel; l sums the same truncated values so
// the softmax normalization cancels the bias to first order.
__device__ __forceinline__ unsigned pkbf_tr(float x, float y) {
#if __has_builtin(__builtin_amdgcn_perm)
  return __builtin_amdgcn_perm(__builtin_bit_cast(unsigned, y),
                               __builtin_bit_cast(unsigned, x), 0x07060302u);
#else
  unsigned a = __builtin_bit_cast(unsigned, x) >> 16;
  unsigned b = __builtin_bit_cast(unsigned, y) & 0xFFFF0000u;
  return a | b;
#endif
}
// gfx950 MFMA-transpose swaps (VALU cross-lane, not DS pipe) — validated R10
__device__ __forceinline__ void pl32swap(unsigned &a, unsigned &b) {
  asm volatile("v_permlane32_swap_b32 %0, %1" : "+v"(a), "+v"(b));
}
__device__ __forceinline__ void pl16swap(unsigned &a, unsigned &b) {
  asm volatile("v_permlane16_swap_b32 %0, %1" : "+v"(a), "+v"(b));
}

// ---------------------------------------------------------------------------
// Prep 1: x (fp32, c-major) -> xb[z][p][c] bf16 pos-major (transpose+convert)
// ---------------------------------------------------------------------------
__global__ __launch_bounds__(256)
void convert_x_kernel(const float* __restrict__ spatial,
                      const float* __restrict__ freq,
                      bf16* __restrict__ xb) {
  const int tid = threadIdx.x;
  const int p0 = blockIdx.x * 64;
  const int c0 = blockIdx.y * 64;
  const int z  = blockIdx.z;            // s*B_ + b
  const int s = z >> 1, b = z & 1;
  const float* x = (s == 0) ? spatial : freq;

  __shared__ float ls[64][65];

  const int pp = tid & 63, cb = tid >> 6;
  #pragma unroll
  for (int i = 0; i < 16; ++i) {
    int c = cb + 4 * i;
    ls[c][pp] = x[(size_t)(b * C_ + c0 + c) * N_ + p0 + pp];
  }
  __syncthreads();

  #pragma unroll
  for (int i = 0; i < 2; ++i) {
    int j = tid + 256 * i;              // 0..511
    int p = j >> 3, ck = (j & 7) * 8;
    short tmp[8];
    #pragma unroll
    for (int u = 0; u < 8; ++u) tmp[u] = fbs(ls[ck + u][p]);
    *(sx8*)(xb + ((size_t)z * N_ + p0 + p) * C_ + c0 + ck) = *(sx8*)tmp;
  }
}

// ---------------------------------------------------------------------------
// Prep 2: weights -> bf16. wb = stacked [wq;wk;wv] (768x256), wob = wo.
// ---------------------------------------------------------------------------
__global__ __launch_bounds__(256)
void convert_w_kernel(const float* __restrict__ wq, const float* __restrict__ wk,
                      const float* __restrict__ wv, const float* __restrict__ wo,
                      bf16* __restrict__ wb, bf16* __restrict__ wob) {
  int idx = blockIdx.x * 256 + threadIdx.x;     // 0..262143
  if (idx < 196608) {
    const float* src = (idx < 65536) ? wq : (idx < 131072) ? wk : wv;
    wb[idx] = f2b(src[idx & 65535]);
  } else {
    int off = idx - 196608;
    wob[off] = f2b(wo[off]);
  }
}

// ---------------------------------------------------------------------------
// Kernel 1: QKV projection as MFMA GEMM. D = W (768x256) * x (256x4096) per z.
//   qhf/khf: per-head pos-major [z][h][n][d32]   (Q pre-scaled by QSC_)
//   vhf:     frag-blocked [z][h][n>>5][d>>4][d&15][n&31]
// grid (N_/128, 768/128, 2*B_), block 256 (4 waves, each 64x64)
// ---------------------------------------------------------------------------
__global__ __launch_bounds__(256)
void qkv_gemm_kernel(const bf16* __restrict__ wb, const bf16* __restrict__ xb,
                     const float* __restrict__ bq, const float* __restrict__ bk,
                     const float* __restrict__ bv,
                     bf16* __restrict__ qhf, bf16* __restrict__ khf,
                     bf16* __restrict__ vhf) {
  const int tid = threadIdx.x;
  const int p0 = blockIdx.x * 128;
  const int o0 = blockIdx.y * 128;
  const int z  = blockIdx.z;

  const int lane = tid & 63, w = tid >> 6;
  const int ml = lane & 15, Q4 = (lane >> 4) * 4, Q8 = (lane >> 4) * 8;
  const int ow = (w >> 1) * 64, pw = (w & 1) * 64;

  __shared__ __align__(16) short asb[128 * 72];
  __shared__ __align__(16) short bsb[128 * 72];
  __shared__ float bias_s[128];

  if (tid < 128) {
    int o = o0 + tid;
    bias_s[tid] = (o < 256) ? bq[o] : (o < 512) ? bk[o - 256] : bv[o - 512];
  }

  const fx4 z4 = {0.f, 0.f, 0.f, 0.f};
  fx4 acc[4][4];
  #pragma unroll
  for (int ot = 0; ot < 4; ++ot)
    #pragma unroll
    for (int pt = 0; pt < 4; ++pt) acc[ot][pt] = z4;

  const int sr = tid >> 1, scu = (tid & 1) * 32;
  for (int k0 = 0; k0 < 256; k0 += 64) {
    __syncthreads();
    #pragma unroll
    for (int u = 0; u < 4; ++u) {
      *(sx8*)&asb[sr * 72 + scu + u * 8] =
          *(const sx8*)&wb[(o0 + sr) * 256 + k0 + scu + u * 8];
      *(sx8*)&bsb[sr * 72 + scu + u * 8] =
          *(const sx8*)(xb + ((size_t)z * N_ + p0 + sr) * C_ + k0 + scu + u * 8);
    }
    __syncthreads();
    #pragma unroll
    for (int kk = 0; kk < 2; ++kk) {
      sx8 af[4], bfr[4];
      #pragma unroll
      for (int t = 0; t < 4; ++t)
        af[t] = *(sx8*)&asb[(ow + t * 16 + ml) * 72 + kk * 32 + Q8];
      #pragma unroll
      for (int t = 0; t < 4; ++t)
        bfr[t] = *(sx8*)&bsb[(pw + t * 16 + ml) * 72 + kk * 32 + Q8];
      #pragma unroll
      for (int ot = 0; ot < 4; ++ot)
        #pragma unroll
        for (int pt = 0; pt < 4; ++pt)
          acc[ot][pt] = __builtin_amdgcn_mfma_f32_16x16x32_bf16(
              af[ot], bfr[pt], acc[ot][pt], 0, 0, 0);
    }
  }

  if (o0 < 512) {
    bf16* dst = (o0 < 256) ? qhf : khf;
    const int ob = (o0 < 256) ? o0 : o0 - 256;
    const float scl = (o0 < 256) ? QSC_ : 1.f;
    #pragma unroll
    for (int ot = 0; ot < 4; ++ot) {
      const int og = ob + ow + ot * 16 + Q4;    // global o, head = og>>5
      #pragma unroll
      for (int pt = 0; pt < 4; ++pt) {
        int p = p0 + pw + pt * 16 + ml;
        short tmp[4];
        #pragma unroll
        for (int r = 0; r < 4; ++r)
          tmp[r] = fbs((acc[ot][pt][r] + bias_s[ow + ot * 16 + Q4 + r]) * scl);
        *(sx4*)(dst + (((size_t)z * NH_ + (og >> 5)) * N_ + p) * D_ + (og & 31)) =
            *(sx4*)tmp;
      }
    }
  } else {
    #pragma unroll
    for (int ot = 0; ot < 4; ++ot)
      #pragma unroll
      for (int pt = 0; pt < 4; ++pt) {
        int p = p0 + pw + pt * 16 + ml;
        #pragma unroll
        for (int r = 0; r < 4; ++r) {
          int lo = ow + ot * 16 + Q4 + r;       // local o in [0,128)
          int rho = (o0 - 512) + lo;            // 0..255
          int h = rho >> 5, d = rho & 31;
          size_t basev = ((size_t)z * NH_ + h) * D_ * N_;
          vhf[basev + (size_t)(((p >> 5) * 2) + (d >> 4)) * 512 +
              (d & 15) * 32 + (p & 31)] = f2b(acc[ot][pt][r] + bias_s[lo]);
        }
      }
  }
}

// ---------------------------------------------------------------------------
// Kernel 2: MFMA flash attention. P^T -> B-operand in registers via
// v_permlane{32,16}_swap (R10, bit-exact). P packed by v_perm truncation
// (1 op vs ~10 for RNE). Q-tile 128 -> grid 1024 = 4 blocks/CU for TLP.
// K/V staged in double-buffered LDS; max-free softmax (QSC_ in Q);
// l via ones-row MFMA. grid (N_/128, NH_, 4), block 256 (4 waves, 32 q each)
// ---------------------------------------------------------------------------
__global__ __launch_bounds__(256, 4)
void attn_kernel(const bf16* __restrict__ qhf, const bf16* __restrict__ khf,
                 const bf16* __restrict__ vhf, bf16* __restrict__ attoT) {
  const int tid  = threadIdx.x;
  const int m0   = blockIdx.x * 128;
  const int h    = blockIdx.y;
  const int z    = blockIdx.z;          // s*B_ + b
  const int s = z >> 1, b = z & 1;
  const int zo = ((1 - s) << 1) | b;    // kv source

  const bf16* qz = qhf + ((size_t)z  * NH_ + h) * N_ * D_;
  const bf16* kz = khf + ((size_t)zo * NH_ + h) * N_ * D_;
  const bf16* vz = vhf + ((size_t)zo * NH_ + h) * D_ * N_;

  const int lane = tid & 63;
  const int w    = tid >> 6;
  const int ml   = lane & 15;
  const int q4   = lane >> 4;           // quad 0..3
  const int Q4   = q4 * 4;
  const int Q8   = q4 * 8;

  // double-buffered K/V tiles (XOR-swizzled kts)
  __shared__ __align__(16) short kts[2][64 * 32];       // 8 KB
  __shared__ __align__(16) short vss[2][4][16 * 36];    // 9 KB

  // Q fragments (B-operand): strip s4 -> row m0 + w*32 + s4*16 + ml
  sx8 qf[2];
  #pragma unroll
  for (int s4 = 0; s4 < 2; ++s4)
    qf[s4] = *(const sx8*)(qz + (size_t)(m0 + w * 32 + s4 * 16 + ml) * D_ + Q8);

  sx8 onesf;                            // bf16 1.0 row for the l-sum MFMA
  #pragma unroll
  for (int u = 0; u < 8; ++u) onesf[u] = (short)0x3F80;

  const fx4 z4 = {0.f, 0.f, 0.f, 0.f};
  fx4 acc[2][2] = {{z4, z4}, {z4, z4}};
  fx4 lacc[2] = {z4, z4};

  // staging coords (lane-constant swizzles)
  const int srow = tid >> 2;                              // K: row n 0..63
  const int ksw  = ((tid & 3) ^ (srow & 3)) * 8;          //    phys d-granule
  const int vblk = tid >> 6, vrow = (tid >> 2) & 15, vg = (tid & 3) * 8;
  const int kfg  = (q4 ^ (ml & 3)) * 8;                   // kts read granule

  sx8 kpre = *(const sx8*)(kz + (size_t)tid * 8);
  sx8 vpre = *(const sx8*)(vz + (size_t)tid * 8);
  *(sx8*)&kts[0][srow * 32 + ksw] = kpre;
  *(sx8*)&vss[0][vblk][vrow * 36 + vg] = vpre;
  __syncthreads();

  int cur = 0;
  for (int n0 = 0; n0 < N_; n0 += 64) {
    const bool more = (n0 + 64 < N_);
    if (more) {
      kpre = *(const sx8*)(kz + (size_t)(n0 + 64) * D_ + (size_t)tid * 8);
      vpre = *(const sx8*)(vz + (size_t)(n0 + 64) * D_ + (size_t)tid * 8);
    }

    // fragments from LDS (shared across both strips)
    sx8 kf[4], vf[2][2];
    #pragma unroll
    for (int t = 0; t < 4; ++t)
      kf[t] = *(sx8*)&kts[cur][(t * 16 + ml) * 32 + kfg];
    #pragma unroll
    for (int dt = 0; dt < 2; ++dt)
      #pragma unroll
      for (int c = 0; c < 2; ++c)
        vf[dt][c] = *(sx8*)&vss[cur][c * 2 + dt][ml * 36 + Q8];

    #pragma unroll
    for (int s4 = 0; s4 < 2; ++s4) {
      fx4 st[4];
      #pragma unroll
      for (int t = 0; t < 4; ++t)
        st[t] = __builtin_amdgcn_mfma_f32_16x16x32_bf16(kf[t], qf[s4], z4, 0, 0, 0);

      // exp + truncate-pack each tile's 4 values into 2 dwords (1 perm each)
      unsigned T[4][2];
      #pragma unroll
      for (int t = 0; t < 4; ++t) {
        float e0 = fexp2(st[t][0]), e1 = fexp2(st[t][1]);
        float e2 = fexp2(st[t][2]), e3 = fexp2(st[t][3]);
        T[t][0] = pkbf_tr(e0, e1);
        T[t][1] = pkbf_tr(e2, e3);
      }
      // in-register C-layout -> B-operand transform (validated R10)
      pl32swap(T[0][0], T[1][0]); pl16swap(T[0][0], T[1][0]);
      pl32swap(T[0][1], T[1][1]); pl16swap(T[0][1], T[1][1]);
      pl32swap(T[2][0], T[3][0]); pl16swap(T[2][0], T[3][0]);
      pl32swap(T[2][1], T[3][1]); pl16swap(T[2][1], T[3][1]);
      ix4 p0 = {(int)T[0][0], (int)T[0][1], (int)T[1][0], (int)T[1][1]};
      ix4 p1 = {(int)T[2][0], (int)T[2][1], (int)T[3][0], (int)T[3][1]};
      sx8 pf0 = *(sx8*)&p0;
      sx8 pf1 = *(sx8*)&p1;

      lacc[s4] = __builtin_amdgcn_mfma_f32_16x16x32_bf16(onesf, pf0, lacc[s4], 0, 0, 0);
      lacc[s4] = __builtin_amdgcn_mfma_f32_16x16x32_bf16(onesf, pf1, lacc[s4], 0, 0, 0);
      #pragma unroll
      for (int dt = 0; dt < 2; ++dt) {
        fx4 a = acc[s4][dt];
        a = __builtin_amdgcn_mfma_f32_16x16x32_bf16(vf[dt][0], pf0, a, 0, 0, 0);
        a = __builtin_amdgcn_mfma_f32_16x16x32_bf16(vf[dt][1], pf1, a, 0, 0, 0);
        acc[s4][dt] = a;
      }
    }

    // write prefetched next tile into the idle buffer, then ONE barrier
    if (more) {
      *(sx8*)&kts[cur ^ 1][srow * 32 + ksw] = kpre;
      *(sx8*)&vss[cur ^ 1][vblk][vrow * 36 + vg] = vpre;
    }
    __syncthreads();
    cur ^= 1;
  }

  // epilogue: l for this lane's query column is lacc[s4][0] (all rows equal)
  #pragma unroll
  for (int s4 = 0; s4 < 2; ++s4) {
    float inv = 1.f / lacc[s4][0];
    int col = m0 + w * 32 + s4 * 16 + ml;
    #pragma unroll
    for (int dt = 0; dt < 2; ++dt) {
      short tmp[4];
      #pragma unroll
      for (int r = 0; r < 4; ++r) tmp[r] = fbs(acc[s4][dt][r] * inv);
      *(sx4*)(attoT + ((size_t)z * N_ + col) * C_ + h * D_ + dt * 16 + Q4) =
          *(sx4*)tmp;
    }
  }
}

// ---------------------------------------------------------------------------
// Kernel 3: out_proj as MFMA GEMM. D = Wo * (attS + attF), residuals fused.
// ---------------------------------------------------------------------------
__global__ __launch_bounds__(256)
void out_proj_kernel(const bf16* __restrict__ wob, const bf16* __restrict__ attoT,
                     const float* __restrict__ spatial,
                     const float* __restrict__ freq,
                     const float* __restrict__ bo, float* __restrict__ out) {
  const int tid = threadIdx.x;
  const int p0 = blockIdx.x * 128;
  const int o0 = blockIdx.y * 64;
  const int b  = blockIdx.z;

  const int lane = tid & 63, w = tid >> 6;
  const int ml = lane & 15, Q4 = (lane >> 4) * 4, Q8 = (lane >> 4) * 8;
  const int ow = (w >> 1) * 32, pw = (w & 1) * 64;

  __shared__ __align__(16) short asb[64 * 72];
  __shared__ __align__(16) short bsb[128 * 72];
  __shared__ float bo_s[64];

  if (tid < 64) bo_s[tid] = 2.f * bo[o0 + tid];

  const bf16* at0 = attoT + (size_t)(0 + b) * N_ * C_;   // s=0 slice
  const bf16* at1 = attoT + (size_t)(2 + b) * N_ * C_;   // s=1 slice

  const fx4 z4 = {0.f, 0.f, 0.f, 0.f};
  fx4 acc[2][4];
  #pragma unroll
  for (int ot = 0; ot < 2; ++ot)
    #pragma unroll
    for (int pt = 0; pt < 4; ++pt) acc[ot][pt] = z4;

  for (int k0 = 0; k0 < 256; k0 += 64) {
    __syncthreads();
    #pragma unroll
    for (int i = 0; i < 2; ++i) {
      int j = tid + 256 * i;            // 0..511
      int r = j >> 3, cu = (j & 7) * 8;
      *(sx8*)&asb[r * 72 + cu] = *(const sx8*)&wob[(o0 + r) * 256 + k0 + cu];
    }
    #pragma unroll
    for (int i = 0; i < 4; ++i) {
      int j = tid + 256 * i;            // 0..1023
      int p = j >> 3, cu = (j & 7) * 8;
      sx8 va = *(const sx8*)(at0 + (size_t)(p0 + p) * C_ + k0 + cu);
      sx8 vb2 = *(const sx8*)(at1 + (size_t)(p0 + p) * C_ + k0 + cu);
      short tmp[8];
      #pragma unroll
      for (int u = 0; u < 8; ++u) tmp[u] = fbs(sbf(va[u]) + sbf(vb2[u]));
      *(sx8*)&bsb[p * 72 + cu] = *(sx8*)tmp;
    }
    __syncthreads();
    #pragma unroll
    for (int kk = 0; kk < 2; ++kk) {
      sx8 af[2], bfr[4];
      #pragma unroll
      for (int t = 0; t < 2; ++t)
        af[t] = *(sx8*)&asb[(ow + t * 16 + ml) * 72 + kk * 32 + Q8];
      #pragma unroll
      for (int t = 0; t < 4; ++t)
        bfr[t] = *(sx8*)&bsb[(pw + t * 16 + ml) * 72 + kk * 32 + Q8];
      #pragma unroll
      for (int ot = 0; ot < 2; ++ot)
        #pragma unroll
        for (int pt = 0; pt < 4; ++pt)
          acc[ot][pt] = __builtin_amdgcn_mfma_f32_16x16x32_bf16(
              af[ot], bfr[pt], acc[ot][pt], 0, 0, 0);
    }
  }

  #pragma unroll
  for (int ot = 0; ot < 2; ++ot)
    #pragma unroll
    for (int pt = 0; pt < 4; ++pt) {
      int p = p0 + pw + pt * 16 + ml;
      #pragma unroll
      for (int r = 0; r < 4; ++r) {
        int ol = ow + ot * 16 + Q4 + r;
        size_t off = ((size_t)b * C_ + o0 + ol) * N_ + p;
        out[off] = acc[ot][pt][r] + bo_s[ol] + spatial[off] + freq[off];
      }
    }
}

extern "C" void kernel_launch(void* const* d_in, const int* in_sizes, int n_in,
                              void* d_out, int out_size, void* d_ws, size_t ws_size,
                              hipStream_t stream) {
  const float* spatial = (const float*)d_in[0];
  const float* freq    = (const float*)d_in[1];
  const float* wq = (const float*)d_in[2];
  const float* bq = (const float*)d_in[3];
  const float* wk = (const float*)d_in[4];
  const float* bk = (const float*)d_in[5];
  const float* wv = (const float*)d_in[6];
  const float* bv = (const float*)d_in[7];
  const float* wo = (const float*)d_in[8];
  const float* bo = (const float*)d_in[9];
  float* out = (float*)d_out;

  // workspace layout (bf16 elements)
  const size_t SZ = (size_t)2 * B_ * N_ * C_;   // 4.19M elems = 8.4 MB
  bf16* xb    = (bf16*)d_ws;                    // [z][p][c]
  bf16* qhf   = xb + SZ;                        // [z][h][n][d]
  bf16* khf   = qhf + SZ;                       // [z][h][n][d]
  bf16* vhf   = khf + SZ;                       // [z][h] frag-blocked
  bf16* attoT = vhf + SZ;                       // [z][p][c]
  bf16* wb    = attoT + SZ;                     // [768][256]
  bf16* wob   = wb + 768 * 256;                 // [256][256]

  convert_w_kernel<<<dim3(1024), 256, 0, stream>>>(wq, wk, wv, wo, wb, wob);
  convert_x_kernel<<<dim3(N_ / 64, C_ / 64, 2 * B_), 256, 0, stream>>>(
      spatial, freq, xb);
  qkv_gemm_kernel<<<dim3(N_ / 128, 768 / 128, 2 * B_), 256, 0, stream>>>(
      wb, xb, bq, bk, bv, qhf, khf, vhf);
  attn_kernel<<<dim3(N_ / 128, NH_, 2 * B_), 256, 0, stream>>>(
      qhf, khf, vhf, attoT);
  out_proj_kernel<<<dim3(N_ / 128, C_ / 64, B_), 256, 0, stream>>>(
      wob, attoT, spatial, freq, bo, out);
}

// Round 12
// 208.423 us; speedup vs baseline: 1.1105x; 1.0105x over previous
//
#include <hip/hip_runtime.h>
#include <hip/hip_bf16.h>

#define B_ 2
#define C_ 256
#define NH_ 8
#define D_ 32
#define N_ 4096
#define SCALE_ 0.17677669529663689f
// SCALE * log2(e): folded into Q so softmax is a bare v_exp_f32 per score
#define QSC_ 0.25505277f

typedef __hip_bfloat16 bf16;
typedef __attribute__((ext_vector_type(8))) short sx8;   // 8 bf16 = one MFMA A/B frag
typedef __attribute__((ext_vector_type(4))) short sx4;
typedef __attribute__((ext_vector_type(4))) float fx4;   // MFMA C/D frag
typedef __attribute__((ext_vector_type(4))) int ix4;

__device__ __forceinline__ float b2f(bf16 x) { return __bfloat162float(x); }
__device__ __forceinline__ bf16 f2b(float x) { return __float2bfloat16(x); }
__device__ __forceinline__ short fbs(float x) { bf16 h = __float2bfloat16(x); return *(short*)&h; }
__device__ __forceinline__ float sbf(short s) { bf16 h = *(bf16*)&s; return __bfloat162float(h); }

#if __has_builtin(__builtin_amdgcn_exp2f)
__device__ __forceinline__ float fexp2(float x) { return __builtin_amdgcn_exp2f(x); }
#else
__device__ __forceinline__ float fexp2(float x) { return exp2f(x); }
#endif

// pack two f32 -> one dword of two bf16 by TRUNCATION (1 VALU op via v_perm).
// P in (0,1]; l sums the same truncated values so normalization cancels bias.
__device__ __forceinline__ unsigned pkbf_tr(float x, float y) {
#if __has_builtin(__builtin_amdgcn_perm)
  return __builtin_amdgcn_perm(__builtin_bit_cast(unsigned, y),
                               __builtin_bit_cast(unsigned, x), 0x07060302u);
#else
  unsigned a = __builtin_bit_cast(unsigned, x) >> 16;
  unsigned b = __builtin_bit_cast(unsigned, y) & 0xFFFF0000u;
  return a | b;
#endif
}
// gfx950 MFMA-transpose swaps (VALU cross-lane, not DS pipe) — validated R10
__device__ __forceinline__ void pl32swap(unsigned &a, unsigned &b) {
  asm volatile("v_permlane32_swap_b32 %0, %1" : "+v"(a), "+v"(b));
}
__device__ __forceinline__ void pl16swap(unsigned &a, unsigned &b) {
  asm volatile("v_permlane16_swap_b32 %0, %1" : "+v"(a), "+v"(b));
}

// ---------------------------------------------------------------------------
// Prep (merged): z<4 -> x transpose+convert to xb[z][p][c];
//                z==4 -> weights -> bf16 (wb stacked [wq;wk;wv], wob).
// grid (N_/64, C_/64, 5), block 256
// ---------------------------------------------------------------------------
__global__ __launch_bounds__(256)
void convert_kernel(const float* __restrict__ spatial,
                    const float* __restrict__ freq,
                    const float* __restrict__ wq, const float* __restrict__ wk,
                    const float* __restrict__ wv, const float* __restrict__ wo,
                    bf16* __restrict__ xb, bf16* __restrict__ wb,
                    bf16* __restrict__ wob) {
  const int tid = threadIdx.x;
  if (blockIdx.z == 4) {
    int base = (blockIdx.y * 64 + blockIdx.x) * 256 + tid;   // 0..65535
    #pragma unroll
    for (int i = 0; i < 4; ++i) {
      int idx = base + i * 65536;                            // 0..262143
      if (idx < 196608) {
        const float* src = (idx < 65536) ? wq : (idx < 131072) ? wk : wv;
        wb[idx] = f2b(src[idx & 65535]);
      } else {
        wob[idx - 196608] = f2b(wo[idx - 196608]);
      }
    }
    return;
  }

  const int p0 = blockIdx.x * 64;
  const int c0 = blockIdx.y * 64;
  const int z  = blockIdx.z;            // s*B_ + b
  const int s = z >> 1, b = z & 1;
  const float* x = (s == 0) ? spatial : freq;

  __shared__ float ls[64][65];

  const int pp = tid & 63, cb = tid >> 6;
  #pragma unroll
  for (int i = 0; i < 16; ++i) {
    int c = cb + 4 * i;
    ls[c][pp] = x[(size_t)(b * C_ + c0 + c) * N_ + p0 + pp];
  }
  __syncthreads();

  #pragma unroll
  for (int i = 0; i < 2; ++i) {
    int j = tid + 256 * i;              // 0..511
    int p = j >> 3, ck = (j & 7) * 8;
    short tmp[8];
    #pragma unroll
    for (int u = 0; u < 8; ++u) tmp[u] = fbs(ls[ck + u][p]);
    *(sx8*)(xb + ((size_t)z * N_ + p0 + p) * C_ + c0 + ck) = *(sx8*)tmp;
  }
}

// ---------------------------------------------------------------------------
// Kernel 1: QKV projection as MFMA GEMM. D = W (768x256) * x (256x4096) per z.
//   qhf/khf: per-head pos-major [z][h][n][d32]   (Q pre-scaled by QSC_)
//   vhf:     frag-blocked [z][h][n>>5][d>>4][d&15][n&31]
// grid (N_/128, 768/128, 2*B_), block 256 (4 waves, each 64x64)
// ---------------------------------------------------------------------------
__global__ __launch_bounds__(256)
void qkv_gemm_kernel(const bf16* __restrict__ wb, const bf16* __restrict__ xb,
                     const float* __restrict__ bq, const float* __restrict__ bk,
                     const float* __restrict__ bv,
                     bf16* __restrict__ qhf, bf16* __restrict__ khf,
                     bf16* __restrict__ vhf) {
  const int tid = threadIdx.x;
  const int p0 = blockIdx.x * 128;
  const int o0 = blockIdx.y * 128;
  const int z  = blockIdx.z;

  const int lane = tid & 63, w = tid >> 6;
  const int ml = lane & 15, Q4 = (lane >> 4) * 4, Q8 = (lane >> 4) * 8;
  const int ow = (w >> 1) * 64, pw = (w & 1) * 64;

  __shared__ __align__(16) short asb[128 * 72];
  __shared__ __align__(16) short bsb[128 * 72];
  __shared__ float bias_s[128];

  if (tid < 128) {
    int o = o0 + tid;
    bias_s[tid] = (o < 256) ? bq[o] : (o < 512) ? bk[o - 256] : bv[o - 512];
  }

  const fx4 z4 = {0.f, 0.f, 0.f, 0.f};
  fx4 acc[4][4];
  #pragma unroll
  for (int ot = 0; ot < 4; ++ot)
    #pragma unroll
    for (int pt = 0; pt < 4; ++pt) acc[ot][pt] = z4;

  const int sr = tid >> 1, scu = (tid & 1) * 32;
  for (int k0 = 0; k0 < 256; k0 += 64) {
    __syncthreads();
    #pragma unroll
    for (int u = 0; u < 4; ++u) {
      *(sx8*)&asb[sr * 72 + scu + u * 8] =
          *(const sx8*)&wb[(o0 + sr) * 256 + k0 + scu + u * 8];
      *(sx8*)&bsb[sr * 72 + scu + u * 8] =
          *(const sx8*)(xb + ((size_t)z * N_ + p0 + sr) * C_ + k0 + scu + u * 8);
    }
    __syncthreads();
    #pragma unroll
    for (int kk = 0; kk < 2; ++kk) {
      sx8 af[4], bfr[4];
      #pragma unroll
      for (int t = 0; t < 4; ++t)
        af[t] = *(sx8*)&asb[(ow + t * 16 + ml) * 72 + kk * 32 + Q8];
      #pragma unroll
      for (int t = 0; t < 4; ++t)
        bfr[t] = *(sx8*)&bsb[(pw + t * 16 + ml) * 72 + kk * 32 + Q8];
      #pragma unroll
      for (int ot = 0; ot < 4; ++ot)
        #pragma unroll
        for (int pt = 0; pt < 4; ++pt)
          acc[ot][pt] = __builtin_amdgcn_mfma_f32_16x16x32_bf16(
              af[ot], bfr[pt], acc[ot][pt], 0, 0, 0);
    }
  }

  if (o0 < 512) {
    bf16* dst = (o0 < 256) ? qhf : khf;
    const int ob = (o0 < 256) ? o0 : o0 - 256;
    const float scl = (o0 < 256) ? QSC_ : 1.f;
    #pragma unroll
    for (int ot = 0; ot < 4; ++ot) {
      const int og = ob + ow + ot * 16 + Q4;    // global o, head = og>>5
      #pragma unroll
      for (int pt = 0; pt < 4; ++pt) {
        int p = p0 + pw + pt * 16 + ml;
        short tmp[4];
        #pragma unroll
        for (int r = 0; r < 4; ++r)
          tmp[r] = fbs((acc[ot][pt][r] + bias_s[ow + ot * 16 + Q4 + r]) * scl);
        *(sx4*)(dst + (((size_t)z * NH_ + (og >> 5)) * N_ + p) * D_ + (og & 31)) =
            *(sx4*)tmp;
      }
    }
  } else {
    #pragma unroll
    for (int ot = 0; ot < 4; ++ot)
      #pragma unroll
      for (int pt = 0; pt < 4; ++pt) {
        int p = p0 + pw + pt * 16 + ml;
        #pragma unroll
        for (int r = 0; r < 4; ++r) {
          int lo = ow + ot * 16 + Q4 + r;       // local o in [0,128)
          int rho = (o0 - 512) + lo;            // 0..255
          int h = rho >> 5, d = rho & 31;
          size_t basev = ((size_t)z * NH_ + h) * D_ * N_;
          vhf[basev + (size_t)(((p >> 5) * 2) + (d >> 4)) * 512 +
              (d & 15) * 32 + (p & 31)] = f2b(acc[ot][pt][r] + bias_s[lo]);
        }
      }
  }
}

// ---------------------------------------------------------------------------
// Kernel 2: MFMA flash attention. KV-tile 128 processed as 2 sequential
// 64-key halves per barrier period -> HALF the block barriers of R11 with
// R11-level register pressure. P^T -> B-operand in registers via
// v_permlane{32,16}_swap; P packed by v_perm truncation; max-free softmax;
// l via ones-row MFMA. grid (N_/128, NH_, 4), block 256 (4 waves, 32 q each)
// ---------------------------------------------------------------------------
__global__ __launch_bounds__(256, 4)
void attn_kernel(const bf16* __restrict__ qhf, const bf16* __restrict__ khf,
                 const bf16* __restrict__ vhf, bf16* __restrict__ attoT) {
  const int tid  = threadIdx.x;
  const int m0   = blockIdx.x * 128;
  const int h    = blockIdx.y;
  const int z    = blockIdx.z;          // s*B_ + b
  const int s = z >> 1, b = z & 1;
  const int zo = ((1 - s) << 1) | b;    // kv source

  const bf16* qz = qhf + ((size_t)z  * NH_ + h) * N_ * D_;
  const bf16* kz = khf + ((size_t)zo * NH_ + h) * N_ * D_;
  const bf16* vz = vhf + ((size_t)zo * NH_ + h) * D_ * N_;

  const int lane = tid & 63;
  const int w    = tid >> 6;
  const int ml   = lane & 15;
  const int q4   = lane >> 4;           // quad 0..3
  const int Q4   = q4 * 4;
  const int Q8   = q4 * 8;

  // double-buffered 128-key K/V tiles
  __shared__ __align__(16) short kts[2][128 * 32];      // 16 KB (XOR-swizzled)
  __shared__ __align__(16) short vss[2][8][16 * 36];    // 18.4 KB

  // Q fragments (B-operand): strip s4 -> row m0 + w*32 + s4*16 + ml
  sx8 qf[2];
  #pragma unroll
  for (int s4 = 0; s4 < 2; ++s4)
    qf[s4] = *(const sx8*)(qz + (size_t)(m0 + w * 32 + s4 * 16 + ml) * D_ + Q8);

  sx8 onesf;                            // bf16 1.0 row for the l-sum MFMA
  #pragma unroll
  for (int u = 0; u < 8; ++u) onesf[u] = (short)0x3F80;

  const fx4 z4 = {0.f, 0.f, 0.f, 0.f};
  fx4 acc[2][2] = {{z4, z4}, {z4, z4}};
  fx4 lacc[2] = {z4, z4};

  // staging coords (lane-constant swizzles). Thread moves 2x16B for K and V.
  const int srow = tid >> 2;                              // K row (and +64)
  const int ksw  = ((tid & 3) ^ (srow & 3)) * 8;          // phys d-granule
  const int vb1  = tid >> 6;            // V dest block for first 16B (0..3)
  const int vrow = (tid >> 2) & 15, vg = (tid & 3) * 8;
  const int kfg  = (q4 ^ (ml & 3)) * 8;                   // kts read granule

  sx8 kpA = *(const sx8*)(kz + (size_t)tid * 8);
  sx8 kpB = *(const sx8*)(kz + 2048 + (size_t)tid * 8);
  sx8 vpA = *(const sx8*)(vz + (size_t)tid * 8);
  sx8 vpB = *(const sx8*)(vz + 2048 + (size_t)tid * 8);
  *(sx8*)&kts[0][srow * 32 + ksw] = kpA;
  *(sx8*)&kts[0][(64 + srow) * 32 + ksw] = kpB;
  *(sx8*)&vss[0][vb1][vrow * 36 + vg] = vpA;
  *(sx8*)&vss[0][4 + vb1][vrow * 36 + vg] = vpB;
  __syncthreads();

  int cur = 0;
  for (int n0 = 0; n0 < N_; n0 += 128) {
    const bool more = (n0 + 128 < N_);
    if (more) {
      size_t base = (size_t)(n0 + 128) * D_ + (size_t)tid * 8;
      kpA = *(const sx8*)(kz + base);
      kpB = *(const sx8*)(kz + base + 2048);
      vpA = *(const sx8*)(vz + base);
      vpB = *(const sx8*)(vz + base + 2048);
    }

    #pragma unroll
    for (int half = 0; half < 2; ++half) {
      // fragments for this 64-key half (shared across both strips)
      sx8 kf[4], vf[2][2];
      #pragma unroll
      for (int t = 0; t < 4; ++t)
        kf[t] = *(sx8*)&kts[cur][(half * 64 + t * 16 + ml) * 32 + kfg];
      #pragma unroll
      for (int dt = 0; dt < 2; ++dt)
        #pragma unroll
        for (int c = 0; c < 2; ++c)
          vf[dt][c] = *(sx8*)&vss[cur][(half * 2 + c) * 2 + dt][ml * 36 + Q8];

      #pragma unroll
      for (int s4 = 0; s4 < 2; ++s4) {
        fx4 st[4];
        #pragma unroll
        for (int t = 0; t < 4; ++t)
          st[t] = __builtin_amdgcn_mfma_f32_16x16x32_bf16(kf[t], qf[s4], z4, 0, 0, 0);

        // exp + truncate-pack each tile's 4 values into 2 dwords
        unsigned T[4][2];
        #pragma unroll
        for (int t = 0; t < 4; ++t) {
          float e0 = fexp2(st[t][0]), e1 = fexp2(st[t][1]);
          float e2 = fexp2(st[t][2]), e3 = fexp2(st[t][3]);
          T[t][0] = pkbf_tr(e0, e1);
          T[t][1] = pkbf_tr(e2, e3);
        }
        // in-register C-layout -> B-operand transform (validated R10)
        pl32swap(T[0][0], T[1][0]); pl16swap(T[0][0], T[1][0]);
        pl32swap(T[0][1], T[1][1]); pl16swap(T[0][1], T[1][1]);
        pl32swap(T[2][0], T[3][0]); pl16swap(T[2][0], T[3][0]);
        pl32swap(T[2][1], T[3][1]); pl16swap(T[2][1], T[3][1]);
        ix4 p0 = {(int)T[0][0], (int)T[0][1], (int)T[1][0], (int)T[1][1]};
        ix4 p1 = {(int)T[2][0], (int)T[2][1], (int)T[3][0], (int)T[3][1]};
        sx8 pf0 = *(sx8*)&p0;
        sx8 pf1 = *(sx8*)&p1;

        lacc[s4] = __builtin_amdgcn_mfma_f32_16x16x32_bf16(onesf, pf0, lacc[s4], 0, 0, 0);
        lacc[s4] = __builtin_amdgcn_mfma_f32_16x16x32_bf16(onesf, pf1, lacc[s4], 0, 0, 0);
        #pragma unroll
        for (int dt = 0; dt < 2; ++dt) {
          fx4 a = acc[s4][dt];
          a = __builtin_amdgcn_mfma_f32_16x16x32_bf16(vf[dt][0], pf0, a, 0, 0, 0);
          a = __builtin_amdgcn_mfma_f32_16x16x32_bf16(vf[dt][1], pf1, a, 0, 0, 0);
          acc[s4][dt] = a;
        }
      }
    }

    // write prefetched next 128-tile into the idle buffer, then ONE barrier
    if (more) {
      *(sx8*)&kts[cur ^ 1][srow * 32 + ksw] = kpA;
      *(sx8*)&kts[cur ^ 1][(64 + srow) * 32 + ksw] = kpB;
      *(sx8*)&vss[cur ^ 1][vb1][vrow * 36 + vg] = vpA;
      *(sx8*)&vss[cur ^ 1][4 + vb1][vrow * 36 + vg] = vpB;
    }
    __syncthreads();
    cur ^= 1;
  }

  // epilogue: l for this lane's query column is lacc[s4][0] (all rows equal)
  #pragma unroll
  for (int s4 = 0; s4 < 2; ++s4) {
    float inv = 1.f / lacc[s4][0];
    int col = m0 + w * 32 + s4 * 16 + ml;
    #pragma unroll
    for (int dt = 0; dt < 2; ++dt) {
      short tmp[4];
      #pragma unroll
      for (int r = 0; r < 4; ++r) tmp[r] = fbs(acc[s4][dt][r] * inv);
      *(sx4*)(attoT + ((size_t)z * N_ + col) * C_ + h * D_ + dt * 16 + Q4) =
          *(sx4*)tmp;
    }
  }
}

// ---------------------------------------------------------------------------
// Kernel 3: out_proj as MFMA GEMM. D = Wo * (attS + attF), residuals fused.
// ---------------------------------------------------------------------------
__global__ __launch_bounds__(256)
void out_proj_kernel(const bf16* __restrict__ wob, const bf16* __restrict__ attoT,
                     const float* __restrict__ spatial,
                     const float* __restrict__ freq,
                     const float* __restrict__ bo, float* __restrict__ out) {
  const int tid = threadIdx.x;
  const int p0 = blockIdx.x * 128;
  const int o0 = blockIdx.y * 64;
  const int b  = blockIdx.z;

  const int lane = tid & 63, w = tid >> 6;
  const int ml = lane & 15, Q4 = (lane >> 4) * 4, Q8 = (lane >> 4) * 8;
  const int ow = (w >> 1) * 32, pw = (w & 1) * 64;

  __shared__ __align__(16) short asb[64 * 72];
  __shared__ __align__(16) short bsb[128 * 72];
  __shared__ float bo_s[64];

  if (tid < 64) bo_s[tid] = 2.f * bo[o0 + tid];

  const bf16* at0 = attoT + (size_t)(0 + b) * N_ * C_;   // s=0 slice
  const bf16* at1 = attoT + (size_t)(2 + b) * N_ * C_;   // s=1 slice

  const fx4 z4 = {0.f, 0.f, 0.f, 0.f};
  fx4 acc[2][4];
  #pragma unroll
  for (int ot = 0; ot < 2; ++ot)
    #pragma unroll
    for (int pt = 0; pt < 4; ++pt) acc[ot][pt] = z4;

  for (int k0 = 0; k0 < 256; k0 += 64) {
    __syncthreads();
    #pragma unroll
    for (int i = 0; i < 2; ++i) {
      int j = tid + 256 * i;            // 0..511
      int r = j >> 3, cu = (j & 7) * 8;
      *(sx8*)&asb[r * 72 + cu] = *(const sx8*)&wob[(o0 + r) * 256 + k0 + cu];
    }
    #pragma unroll
    for (int i = 0; i < 4; ++i) {
      int j = tid + 256 * i;            // 0..1023
      int p = j >> 3, cu = (j & 7) * 8;
      sx8 va = *(const sx8*)(at0 + (size_t)(p0 + p) * C_ + k0 + cu);
      sx8 vb2 = *(const sx8*)(at1 + (size_t)(p0 + p) * C_ + k0 + cu);
      short tmp[8];
      #pragma unroll
      for (int u = 0; u < 8; ++u) tmp[u] = fbs(sbf(va[u]) + sbf(vb2[u]));
      *(sx8*)&bsb[p * 72 + cu] = *(sx8*)tmp;
    }
    __syncthreads();
    #pragma unroll
    for (int kk = 0; kk < 2; ++kk) {
      sx8 af[2], bfr[4];
      #pragma unroll
      for (int t = 0; t < 2; ++t)
        af[t] = *(sx8*)&asb[(ow + t * 16 + ml) * 72 + kk * 32 + Q8];
      #pragma unroll
      for (int t = 0; t < 4; ++t)
        bfr[t] = *(sx8*)&bsb[(pw + t * 16 + ml) * 72 + kk * 32 + Q8];
      #pragma unroll
      for (int ot = 0; ot < 2; ++ot)
        #pragma unroll
        for (int pt = 0; pt < 4; ++pt)
          acc[ot][pt] = __builtin_amdgcn_mfma_f32_16x16x32_bf16(
              af[ot], bfr[pt], acc[ot][pt], 0, 0, 0);
    }
  }

  #pragma unroll
  for (int ot = 0; ot < 2; ++ot)
    #pragma unroll
    for (int pt = 0; pt < 4; ++pt) {
      int p = p0 + pw + pt * 16 + ml;
      #pragma unroll
      for (int r = 0; r < 4; ++r) {
        int ol = ow + ot * 16 + Q4 + r;
        size_t off = ((size_t)b * C_ + o0 + ol) * N_ + p;
        out[off] = acc[ot][pt][r] + bo_s[ol] + spatial[off] + freq[off];
      }
    }
}

extern "C" void kernel_launch(void* const* d_in, const int* in_sizes, int n_in,
                              void* d_out, int out_size, void* d_ws, size_t ws_size,
                              hipStream_t stream) {
  const float* spatial = (const float*)d_in[0];
  const float* freq    = (const float*)d_in[1];
  const float* wq = (const float*)d_in[2];
  const float* bq = (const float*)d_in[3];
  const float* wk = (const float*)d_in[4];
  const float* bk = (const float*)d_in[5];
  const float* wv = (const float*)d_in[6];
  const float* bv = (const float*)d_in[7];
  const float* wo = (const float*)d_in[8];
  const float* bo = (const float*)d_in[9];
  float* out = (float*)d_out;

  // workspace layout (bf16 elements)
  const size_t SZ = (size_t)2 * B_ * N_ * C_;   // 4.19M elems = 8.4 MB
  bf16* xb    = (bf16*)d_ws;                    // [z][p][c]
  bf16* qhf   = xb + SZ;                        // [z][h][n][d]
  bf16* khf   = qhf + SZ;                       // [z][h][n][d]
  bf16* vhf   = khf + SZ;                       // [z][h] frag-blocked
  bf16* attoT = vhf + SZ;                       // [z][p][c]
  bf16* wb    = attoT + SZ;                     // [768][256]
  bf16* wob   = wb + 768 * 256;                 // [256][256]

  convert_kernel<<<dim3(N_ / 64, C_ / 64, 5), 256, 0, stream>>>(
      spatial, freq, wq, wk, wv, wo, xb, wb, wob);
  qkv_gemm_kernel<<<dim3(N_ / 128, 768 / 128, 2 * B_), 256, 0, stream>>>(
      wb, xb, bq, bk, bv, qhf, khf, vhf);
  attn_kernel<<<dim3(N_ / 128, NH_, 2 * B_), 256, 0, stream>>>(
      qhf, khf, vhf, attoT);
  out_proj_kernel<<<dim3(N_ / 128, C_ / 64, B_), 256, 0, stream>>>(
      wob, attoT, spatial, freq, bo, out);
}